// Round 1
// baseline (514.793 us; speedup 1.0000x reference)
//
#include <hip/hip_runtime.h>

#define NN 128
#define HH 128
#define BB 2
#define KT 4
#define EE 16256
#define TT 9   // T-1 prediction steps

typedef __bf16 v8bf __attribute__((ext_vector_type(8)));
typedef float v4f __attribute__((ext_vector_type(4)));

__device__ __forceinline__ float tanh_fast(float x) {
  // tanh(x) = 1 - 2/(e^{2x}+1); v_exp + v_rcp via HIP fast intrinsics
  return 1.0f - __fdividef(2.0f, __expf(2.0f * x) + 1.0f);
}
__device__ __forceinline__ float sigmoid_fast(float x) {
  return __fdividef(1.0f, 1.0f + __expf(-x));
}
__device__ __forceinline__ unsigned short f2bf(float f) {  // RNE f32->bf16
  unsigned int u = __float_as_uint(f);
  u += 0x7FFFu + ((u >> 16) & 1u);
  return (unsigned short)(u >> 16);
}

// Build W1T[(k*2+u)][h][g] = W_msg1[k][g][u*128+h]  (fp32, for coalesced U/V dots)
// and W2bf[k][g][h] = bf16(W_msg2[k][g][h])          (MFMA B operand, K-contiguous)
__global__ void prep_kernel(const float* __restrict__ W_msg1,
                            const float* __restrict__ W_msg2,
                            float* __restrict__ W1T,
                            unsigned short* __restrict__ W2bf) {
  int idx = blockIdx.x * 256 + threadIdx.x;  // 0..131071
  int ku = idx >> 14, h = (idx >> 7) & 127, g = idx & 127;
  int k = ku >> 1, u = ku & 1;
  W1T[idx] = W_msg1[(k * 128 + g) * 256 + u * 128 + h];
  if (idx < 65536) W2bf[idx] = f2bf(W_msg2[idx]);
}

// One time step. Block = (b, receiver node n). 512 threads = 8 waves.
// Phase 1: msg MLP over this node's 127 incoming edges (MFMA), reduce -> agg row
// Phase 2: GRU update + output MLP -> hidden_new, pred
// Phase 3: U/V rows for the NEXT step from hidden_new (double-buffered UV)
__global__ __launch_bounds__(512)
void step_kernel(const float* __restrict__ data,
                 const float* __restrict__ rel_type,
                 const float* __restrict__ b_msg1,
                 const float* __restrict__ b_msg2,
                 const float* __restrict__ W_hr,
                 const float* __restrict__ W_hi,
                 const float* __restrict__ W_hh,
                 const float* __restrict__ W_ir, const float* __restrict__ b_ir,
                 const float* __restrict__ W_ii, const float* __restrict__ b_ii,
                 const float* __restrict__ W_in, const float* __restrict__ b_in,
                 const float* __restrict__ W_o1, const float* __restrict__ b_o1,
                 const float* __restrict__ W_o2, const float* __restrict__ b_o2,
                 const float* __restrict__ W_o3, const float* __restrict__ b_o3,
                 const float* __restrict__ W1T,
                 const unsigned short* __restrict__ W2bf,
                 float* __restrict__ hidden,
                 const float* __restrict__ UVin,
                 float* __restrict__ UVout,
                 float* __restrict__ outp,
                 int t) {
  __shared__ unsigned short msg1_lds[16384];  // 128x128 bf16, XOR-swizzled (A)
  __shared__ unsigned short w2_lds[16384];    // 128x128 bf16, XOR-swizzled (B = W2[g][h])
  __shared__ float ub_lds[128];               // U[k,b,n,:] + b_msg1[k]
  __shared__ float rel_lds[128];              // rel_type for edge (r -> n), 0 at r==n
  __shared__ float b2_lds[128];
  __shared__ float colsum[8][128];
  __shared__ float agg_lds[128];
  __shared__ float hid_lds[128];
  __shared__ float hn_lds[128];
  __shared__ float ins_lds[6];
  __shared__ float g_r[128], g_i[128], g_hh[128], g_in[128];
  __shared__ float p1_lds[128], p2_lds[128];

  const int tid = threadIdx.x;
  const int lane = tid & 63;
  const int wave = tid >> 6;  // 0..7, owns output rows [wave*16, wave*16+16)
  const int b = blockIdx.x >> 7;
  const int n = blockIdx.x & 127;

  float acc_all[8][4];
#pragma unroll
  for (int c = 0; c < 8; ++c)
#pragma unroll
    for (int r = 0; r < 4; ++r) acc_all[c][r] = 0.f;

  for (int k = 0; k < KT; ++k) {
    // --- stage W2 bf16 -> LDS (swizzled), plus per-k small vectors ---
    const uint4* w2g4 = (const uint4*)(W2bf + k * 16384);
#pragma unroll
    for (int c = 0; c < 4; ++c) {
      int chunk = tid + c * 512;             // 2048 chunks of 16B
      int row = chunk >> 4, cc = chunk & 15;
      uint4 v = w2g4[chunk];
      int off = (row << 8) + (cc << 4);
      off ^= (row & 7) << 4;
      *(uint4*)((char*)w2_lds + off) = v;
    }
    if (tid < 128) {
      ub_lds[tid] = UVin[(((k * 2 + 0) * BB + b) * NN + n) * HH + tid] + b_msg1[k * 128 + tid];
      b2_lds[tid] = b_msg2[k * 128 + tid];
      float rv = 0.f;
      int r = tid;
      if (r != n) {
        int e = r * 127 + (n < r ? n : n - 1);  // sender-major edge order (np.where)
        rv = rel_type[(b * EE + e) * KT + k];
      }
      rel_lds[r] = rv;
    }
    __syncthreads();

    // --- msg1[r][h] = tanh(U[n][h] + V[r][h] + b1) -> bf16 -> swizzled LDS ---
    {
      int r = tid >> 2;
      int h0 = (tid & 3) << 5;
      const float4* vrow = (const float4*)(UVin + (((k * 2 + 1) * BB + b) * NN + r) * HH + h0);
#pragma unroll
      for (int m = 0; m < 4; ++m) {
        float4 va = vrow[m * 2];
        float4 vb = vrow[m * 2 + 1];
        int hb = h0 + m * 8;
        unsigned int p0 = (unsigned)f2bf(tanh_fast(ub_lds[hb + 0] + va.x)) |
                          ((unsigned)f2bf(tanh_fast(ub_lds[hb + 1] + va.y)) << 16);
        unsigned int p1 = (unsigned)f2bf(tanh_fast(ub_lds[hb + 2] + va.z)) |
                          ((unsigned)f2bf(tanh_fast(ub_lds[hb + 3] + va.w)) << 16);
        unsigned int p2 = (unsigned)f2bf(tanh_fast(ub_lds[hb + 4] + vb.x)) |
                          ((unsigned)f2bf(tanh_fast(ub_lds[hb + 5] + vb.y)) << 16);
        unsigned int p3 = (unsigned)f2bf(tanh_fast(ub_lds[hb + 6] + vb.z)) |
                          ((unsigned)f2bf(tanh_fast(ub_lds[hb + 7] + vb.w)) << 16);
        uint4 pk;
        pk.x = p0; pk.y = p1; pk.z = p2; pk.w = p3;
        int off = (r << 8) + (hb << 1);
        off ^= (r & 7) << 4;
        *(uint4*)((char*)msg1_lds + off) = pk;
      }
    }
    __syncthreads();

    // --- layer2 via MFMA 16x16x32 bf16: out[r][g] = sum_h msg1[r][h]*W2[g][h] ---
    v4f acck[8];
#pragma unroll
    for (int c = 0; c < 8; ++c) acck[c] = (v4f){0.f, 0.f, 0.f, 0.f};
#pragma unroll
    for (int ks = 0; ks < 4; ++ks) {
      int ar = wave * 16 + (lane & 15);
      int ac = ks * 64 + ((lane >> 4) << 4);  // byte offset: (ks*32 + (lane>>4)*8) * 2
      int aoff = (ar << 8) + ac;
      aoff ^= (ar & 7) << 4;
      v8bf afrag = *(const v8bf*)((const char*)msg1_lds + aoff);
#pragma unroll
      for (int c = 0; c < 8; ++c) {
        int br = c * 16 + (lane & 15);
        int boff = (br << 8) + ac;
        boff ^= (br & 7) << 4;
        v8bf bfrag = *(const v8bf*)((const char*)w2_lds + boff);
        acck[c] = __builtin_amdgcn_mfma_f32_16x16x32_bf16(afrag, bfrag, acck[c], 0, 0, 0);
      }
    }
    // epilogue: msg2 = tanh(acc + b2), weighted by rel_type, accumulate over k
#pragma unroll
    for (int c = 0; c < 8; ++c) {
      float bb = b2_lds[c * 16 + (lane & 15)];
#pragma unroll
      for (int rg = 0; rg < 4; ++rg) {
        int rowg = wave * 16 + ((lane >> 4) << 2) + rg;  // D: row=(l>>4)*4+reg
        float v = tanh_fast(acck[c][rg] + bb);
        acc_all[c][rg] += v * rel_lds[rowg];
      }
    }
    __syncthreads();  // protect LDS reuse next k
  }

  // --- reduce over edge rows -> agg[b,n,:] (sum_k rel*msg /4, then /6) ---
#pragma unroll
  for (int c = 0; c < 8; ++c) {
    float s = acc_all[c][0] + acc_all[c][1] + acc_all[c][2] + acc_all[c][3];
    s += __shfl_xor(s, 16);
    s += __shfl_xor(s, 32);
    if ((lane >> 4) == 0) colsum[wave][c * 16 + lane] = s;
  }
  __syncthreads();
  if (tid < 128) {
    float s = 0.f;
#pragma unroll
    for (int w = 0; w < 8; ++w) s += colsum[w][tid];
    agg_lds[tid] = s * (1.0f / 24.0f);
    hid_lds[tid] = hidden[(b * NN + n) * HH + tid];
  }
  if (tid >= 128 && tid < 134) ins_lds[tid - 128] = data[((b * 10 + t) * NN + n) * 6 + (tid - 128)];
  __syncthreads();

  // --- GRU gates: 4 lanes per output h, 32-FMA each + shuffle reduce ---
  {
    int h = tid >> 2, q = tid & 3;
    const float4* whr = (const float4*)(W_hr + h * 128 + q * 32);
    const float4* whi = (const float4*)(W_hi + h * 128 + q * 32);
    const float4* whh = (const float4*)(W_hh + h * 128 + q * 32);
    const float4* ag4 = (const float4*)(agg_lds + q * 32);
    float phr = 0.f, phi = 0.f, phh = 0.f;
#pragma unroll
    for (int j = 0; j < 8; ++j) {
      float4 a = ag4[j];
      float4 wr = whr[j], wi = whi[j], wh = whh[j];
      phr += wr.x * a.x + wr.y * a.y + wr.z * a.z + wr.w * a.w;
      phi += wi.x * a.x + wi.y * a.y + wi.z * a.z + wi.w * a.w;
      phh += wh.x * a.x + wh.y * a.y + wh.z * a.z + wh.w * a.w;
    }
    phr += __shfl_xor(phr, 1); phr += __shfl_xor(phr, 2);
    phi += __shfl_xor(phi, 1); phi += __shfl_xor(phi, 2);
    phh += __shfl_xor(phh, 1); phh += __shfl_xor(phh, 2);
    if (q == 0) {
      float dr = b_ir[h], di = b_ii[h], dn = b_in[h];
#pragma unroll
      for (int j = 0; j < 6; ++j) {
        float iv = ins_lds[j];
        dr += W_ir[h * 6 + j] * iv;
        di += W_ii[h * 6 + j] * iv;
        dn += W_in[h * 6 + j] * iv;
      }
      g_r[h] = dr + phr; g_i[h] = di + phi; g_hh[h] = phh; g_in[h] = dn;
    }
  }
  __syncthreads();
  if (tid < 128) {
    float r = sigmoid_fast(g_r[tid]);
    float ii = sigmoid_fast(g_i[tid]);
    float ng = tanh_fast(g_in[tid] + r * g_hh[tid]);
    float hn = (1.0f - ii) * ng + ii * hid_lds[tid];
    hn_lds[tid] = hn;
    hidden[(b * NN + n) * HH + tid] = hn;  // in-place: row owned by this block
  }
  __syncthreads();

  // --- output MLP ---
  {
    int h = tid >> 2, q = tid & 3;
    const float4* w4 = (const float4*)(W_o1 + h * 128 + q * 32);
    const float4* a4 = (const float4*)(hn_lds + q * 32);
    float p = 0.f;
#pragma unroll
    for (int j = 0; j < 8; ++j) {
      float4 w = w4[j]; float4 a = a4[j];
      p += w.x * a.x + w.y * a.y + w.z * a.z + w.w * a.w;
    }
    p += __shfl_xor(p, 1); p += __shfl_xor(p, 2);
    if (q == 0) p1_lds[h] = fmaxf(p + b_o1[h], 0.f);
  }
  __syncthreads();
  {
    int h = tid >> 2, q = tid & 3;
    const float4* w4 = (const float4*)(W_o2 + h * 128 + q * 32);
    const float4* a4 = (const float4*)(p1_lds + q * 32);
    float p = 0.f;
#pragma unroll
    for (int j = 0; j < 8; ++j) {
      float4 w = w4[j]; float4 a = a4[j];
      p += w.x * a.x + w.y * a.y + w.z * a.z + w.w * a.w;
    }
    p += __shfl_xor(p, 1); p += __shfl_xor(p, 2);
    if (q == 0) p2_lds[h] = fmaxf(p + b_o2[h], 0.f);
  }
  __syncthreads();
  if (tid < 48) {
    int i = tid >> 3, oc = tid & 7;
    const float4* w4 = (const float4*)(W_o3 + i * 128 + oc * 16);
    const float4* a4 = (const float4*)(p2_lds + oc * 16);
    float p = 0.f;
#pragma unroll
    for (int j = 0; j < 4; ++j) {
      float4 w = w4[j]; float4 a = a4[j];
      p += w.x * a.x + w.y * a.y + w.z * a.z + w.w * a.w;
    }
    p += __shfl_xor(p, 1); p += __shfl_xor(p, 2); p += __shfl_xor(p, 4);
    if (oc == 0) outp[((b * NN + n) * TT + t) * 6 + i] = ins_lds[i] + p + b_o3[i];
  }

  // --- U/V rows for next step from hidden_new ---
#pragma unroll
  for (int it = 0; it < 2; ++it) {
    int idx = tid + it * 512;           // 1024 outputs: (k,u) x 128 g
    int kh = idx >> 7, g = idx & 127;
    const float* wcol = W1T + kh * 16384 + g;
    float s = 0.f;
#pragma unroll 8
    for (int h = 0; h < 128; ++h) s += wcol[h * 128] * hn_lds[h];
    UVout[((kh * BB + b) * NN + n) * HH + g] = s;
  }
}

extern "C" void kernel_launch(void* const* d_in, const int* in_sizes, int n_in,
                              void* d_out, int out_size, void* d_ws, size_t ws_size,
                              hipStream_t stream) {
  const float* data     = (const float*)d_in[0];
  const float* rel_type = (const float*)d_in[1];
  // d_in[2]=rel_rec, d_in[3]=rel_send: deterministic one-hot, computed analytically
  const float* W_msg1 = (const float*)d_in[4];
  const float* b_msg1 = (const float*)d_in[5];
  const float* W_msg2 = (const float*)d_in[6];
  const float* b_msg2 = (const float*)d_in[7];
  const float* W_hr = (const float*)d_in[8];
  const float* W_hi = (const float*)d_in[9];
  const float* W_hh = (const float*)d_in[10];
  const float* W_ir = (const float*)d_in[11];
  const float* b_ir = (const float*)d_in[12];
  const float* W_ii = (const float*)d_in[13];
  const float* b_ii = (const float*)d_in[14];
  const float* W_in = (const float*)d_in[15];
  const float* b_in = (const float*)d_in[16];
  const float* W_o1 = (const float*)d_in[17];
  const float* b_o1 = (const float*)d_in[18];
  const float* W_o2 = (const float*)d_in[19];
  const float* b_o2 = (const float*)d_in[20];
  const float* W_o3 = (const float*)d_in[21];
  const float* b_o3 = (const float*)d_in[22];
  float* outp = (float*)d_out;

  char* ws = (char*)d_ws;
  float* hidden = (float*)(ws);                       // 131072 B
  float* UVa    = (float*)(ws + 131072);              // 1 MiB
  float* UVb    = (float*)(ws + 131072 + 1048576);    // 1 MiB
  float* W1T    = (float*)(ws + 131072 + 2097152);    // 512 KiB
  unsigned short* W2bf = (unsigned short*)(ws + 131072 + 2097152 + 524288);  // 128 KiB

  hipMemsetAsync(hidden, 0, 131072, stream);  // hidden0 = 0
  hipMemsetAsync(UVa, 0, 1048576, stream);    // U,V of hidden0 = 0
  prep_kernel<<<512, 256, 0, stream>>>(W_msg1, W_msg2, W1T, W2bf);

  for (int t = 0; t < TT; ++t) {
    float* uvin = (t & 1) ? UVb : UVa;
    float* uvout = (t & 1) ? UVa : UVb;
    step_kernel<<<BB * NN, 512, 0, stream>>>(
        data, rel_type, b_msg1, b_msg2, W_hr, W_hi, W_hh,
        W_ir, b_ir, W_ii, b_ii, W_in, b_in,
        W_o1, b_o1, W_o2, b_o2, W_o3, b_o3,
        W1T, W2bf, hidden, uvin, uvout, outp, t);
  }
}